// Round 13
// baseline (6009.619 us; speedup 1.0000x reference)
//
#include <hip/hip_runtime.h>

// LSTM T=16384, B=32, H=96. 32 blocks x 512 thr (8 waves, 2/SIMD). R20/R24 =
// 4580us baseline. R25 (1 read + DPP rebuild) = 4926: removing 16/24 LDS
// reads did NOT help -> LDS-queue model REFUTED. Step = MFMA burst ~350cy
// (18/SIMD x 19.4) + serial chain ~320cy. R22's failure reinterpreted: late
// UNIFORM reads + 8-deep dot chain ran AFTER the burst, not under it.
// R26 (this): shrink the burst 350->233cy. MFMA keeps k in [0,64): 3 tiles x
// 2 kt = 6/wave = 12/SIMD. k in [64,96) on the VALU via R15's VERIFIED XOR
// butterfly: quad-lane s reads ONE per-lane 16B slice h[64+8s..+8) (same-addr
// across quads -> broadcast, conflict-free, early in queue), 4 slots x 4
// chained dot2 (slot d = gate s^d, weights prescaled by ek(s^d); gx seeds
// slot 0 = own gate), 3-op DPP quad butterfly -> lane s holds gate-s's full
// [64,96) sum. ~24 VALU/lane hides under the 233cy burst (co-issue, m114).
// Tail: pre = te_sel(acc) + vpart (+1 op). MFMA C-init = zero.
// Unchanged (HW-verified): B = weights cols (tile t col c -> cell
// 12wv+4t+(c>>2), gate c&3), te=min(h16,2) mirror, quad DPP tail, e_k
// prefold, scaled-domain c, 513-row slot-shifted history, one barrier/step,
// bulk fc flush per 512-step window.

constexpr int HH   = 96;
constexpr int BB   = 32;
constexpr int TT   = 16384;
constexpr int TH   = 512;   // 8 waves, 2 per SIMD
constexpr int NS   = 512;   // h history window
constexpr int ROWP = 104;   // halves per hist row: 208 B, 16B-aligned

typedef _Float16 f16x8 __attribute__((ext_vector_type(8)));
typedef _Float16 f16x2 __attribute__((ext_vector_type(2)));
typedef float    f32x4 __attribute__((ext_vector_type(4)));

__device__ __forceinline__ float dot2_f16(f16x2 a, f16x2 b, float c) {
    float d;
    int ai = __builtin_bit_cast(int, a);
    int bi = __builtin_bit_cast(int, b);
    asm("v_dot2_f32_f16 %0, %1, %2, %3" : "=v"(d) : "v"(ai), "v"(bi), "v"(c));
    return d;
}

template <int CTRL>
__device__ __forceinline__ float dpp_add2(float a, float b) {
    int r = __builtin_amdgcn_mov_dpp(__builtin_bit_cast(int, b), CTRL, 0xF, 0xF, true);
    return a + __builtin_bit_cast(float, r);
}
template <int CTRL>
__device__ __forceinline__ float dpp_bcast(float v) {
    int r = __builtin_amdgcn_mov_dpp(__builtin_bit_cast(int, v), CTRL, 0xF, 0xF, true);
    return __builtin_bit_cast(float, r);
}
constexpr int DPP_XOR1 = 0xB1;  // quad_perm [1,0,3,2]
constexpr int DPP_XOR2 = 0x4E;  // quad_perm [2,3,0,1]
constexpr int DPP_B1   = 0x55;
constexpr int DPP_B2   = 0xAA;
constexpr int DPP_B3   = 0xFF;

#define LOG2E 1.44269504f

__attribute__((amdgpu_flat_work_group_size(TH, TH)))
__global__ void lstm_kernel(const float* __restrict__ x,
                            const float* __restrict__ w_ih,
                            const float* __restrict__ w_hh,
                            const float* __restrict__ b_ih,
                            const float* __restrict__ b_hh,
                            const float* __restrict__ fc_w,
                            const float* __restrict__ fc_b,
                            float* __restrict__ out) {
    __shared__ __align__(16) _Float16 hist[(NS + 1) * ROWP];  // ~104 KB
    __shared__ __align__(16) float xs[NS];                    // 2 KB x window
    __shared__ float fcw_s[HH];

    const int tid = threadIdx.x;
    const int b   = blockIdx.x;
    const int wv  = tid >> 6;   // wave 0..7, owns cells [12wv, 12wv+12)
    const int l   = tid & 63;
    const int h16 = l >> 4;     // k-group 0..3; tail tile = min(h16,2)
    const int rIn = l & 15;     // col within tile
    const int s   = rIn & 3;    // gate 0..3 (quad lane); VALU k-slice index
    const int q   = rIn >> 2;   // cell-sub within tile
    const int te  = (h16 == 3) ? 2 : h16;    // tail tile (h16=3 mirrors 2)
    const int j   = 12 * wv + 4 * te + q;    // this lane's cell 0..95

    // MFMA B fragments (k in [0,64)), e_k-prescaled. Tile t col rIn holds W
    // row (gate s, cell 12wv+4t+q); lane's k slice = kt*32 + 8*h16 + e.
    const float ek_s = (s == 2) ? (-2.0f * LOG2E) : (-LOG2E);
    f16x8 Bw[3][2];
#pragma unroll
    for (int t = 0; t < 3; ++t) {
        const float* wrow = w_hh + (s * HH + 12 * wv + 4 * t + q) * HH;
#pragma unroll
        for (int kt = 0; kt < 2; ++kt) {
            const float* wr = wrow + kt * 32 + 8 * h16;
            f16x8 v;
#pragma unroll
            for (int e = 0; e < 8; ++e) v[e] = (_Float16)(wr[e] * ek_s);
            Bw[t][kt] = v;
        }
    }
#pragma unroll
    for (int t = 0; t < 3; ++t)
#pragma unroll
        for (int kt = 0; kt < 2; ++kt) asm volatile("" : "+v"(Bw[t][kt]));

    // VALU weights, XOR-indexed (slot d = gate s^d), k slice [64+8s, 72+8s),
    // prescaled by ek(gate). Quad lanes share cell j (same te, q).
    f16x2 Wq[4][4];
#pragma unroll
    for (int d = 0; d < 4; ++d) {
        const int g = s ^ d;
        const float ekg = (g == 2) ? (-2.0f * LOG2E) : (-LOG2E);
        const float* wr = w_hh + (g * HH + j) * HH + 64 + 8 * s;
#pragma unroll
        for (int m = 0; m < 4; ++m)
            Wq[d][m] = f16x2{(_Float16)(wr[2 * m] * ekg),
                             (_Float16)(wr[2 * m + 1] * ekg)};
    }
#pragma unroll
    for (int d = 0; d < 4; ++d)
#pragma unroll
        for (int m = 0; m < 4; ++m) asm volatile("" : "+v"(Wq[d][m]));

    const float wih2  = w_ih[s * HH + j] * ek_s;
    const float bias2 = (b_ih[s * HH + j] + b_hh[s * HH + j]) * ek_s;
    const float a_mul = (s == 2) ? (-4.0f * LOG2E) : 1.0f;
    const float a_add = (s == 2) ? (2.0f * LOG2E) : 0.0f;
    const bool  te1 = (h16 == 1), te2 = (h16 >= 2);

    const float fcb = fc_b[0];
    float c = 0.0f;   // scaled domain: c' = -2*log2e * c_true

    for (int i = tid; i < HH; i += TH) fcw_s[i] = fc_w[i];

    // Bulk fc projection for window [t0, t0+NS): h(t0+i) is in hist row i+1.
    auto flush = [&](int t0) {
        for (int i = tid; i < NS; i += TH) {
            const uint2* hr = (const uint2*)(hist + (i + 1) * ROWP);
            float a = 0.0f;
#pragma unroll
            for (int m = 0; m < 24; ++m) {
                uint2 u = hr[m];
                f16x2 p0 = __builtin_bit_cast(f16x2, u.x);
                f16x2 p1 = __builtin_bit_cast(f16x2, u.y);
                a = fmaf((float)p0.x, fcw_s[4 * m + 0], a);
                a = fmaf((float)p0.y, fcw_s[4 * m + 1], a);
                a = fmaf((float)p1.x, fcw_s[4 * m + 2], a);
                a = fmaf((float)p1.y, fcw_s[4 * m + 3], a);
            }
            out[(t0 + i) * BB + b] = a + fcb + xs[i];
        }
    };

    const _Float16* rd_p;  // h(t-1) MFMA k-slice base (8*h16); +4 rows/block
    const _Float16* rd_v;  // h(t-1) VALU slice base (64 + 8*s)
    _Float16*       wr_p;  // h(t) cell slot base

    auto step = [&](float gx, const int ofs) {   // ofs: constant element offset
        const uint4* p = (const uint4*)(rd_p + ofs);
        uint4 u0 = p[0], u1 = p[4];              // kt stride: 32 halves = 64B
        const uint4 vq = *(const uint4*)(rd_v + ofs);  // 16B, per-lane slice
        const f16x8 a0 = __builtin_bit_cast(f16x8, u0);
        const f16x8 a1 = __builtin_bit_cast(f16x8, u1);
        f16x2 hv[4] = {__builtin_bit_cast(f16x2, vq.x),
                       __builtin_bit_cast(f16x2, vq.y),
                       __builtin_bit_cast(f16x2, vq.z),
                       __builtin_bit_cast(f16x2, vq.w)};

        // VALU pipe (hides under MFMA burst): 4 slots x 4 chained dot2.
        float av0 = gx, av1 = 0.0f, av2 = 0.0f, av3 = 0.0f;
#pragma unroll
        for (int m = 0; m < 4; ++m) {
            av0 = dot2_f16(Wq[0][m], hv[m], av0);
            av1 = dot2_f16(Wq[1][m], hv[m], av1);
            av2 = dot2_f16(Wq[2][m], hv[m], av2);
            av3 = dot2_f16(Wq[3][m], hv[m], av3);
        }
        // XOR quad butterfly (R15-verified): lane s ends with gate s's sum.
        const float b0    = dpp_add2<DPP_XOR1>(av0, av1);
        const float b1    = dpp_add2<DPP_XOR1>(av2, av3);
        const float vpart = dpp_add2<DPP_XOR2>(b0, b1);

        // MFMA pipe: k in [0,64), 3 tile-chains x 2 kt, zero C-init.
        f32x4 acc[3] = {{0.f, 0.f, 0.f, 0.f}, {0.f, 0.f, 0.f, 0.f},
                        {0.f, 0.f, 0.f, 0.f}};
#pragma unroll
        for (int t = 0; t < 3; ++t)
            acc[t] = __builtin_amdgcn_mfma_f32_16x16x32_f16(a0, Bw[t][0], acc[t], 0, 0, 0);
#pragma unroll
        for (int t = 0; t < 3; ++t)
            acc[t] = __builtin_amdgcn_mfma_f32_16x16x32_f16(a1, Bw[t][1], acc[t], 0, 0, 0);

        // Rows are replicas -> reg 0 always; 2-cndmask tile select by te.
        float pre = te1 ? acc[1][0] : acc[0][0];
        pre       = te2 ? acc[2][0] : pre;
        pre += vpart;

        const float act =
            fmaf(__builtin_amdgcn_rcpf(1.0f + __builtin_amdgcn_exp2f(pre)),
                 a_mul, a_add);
        const float fv = dpp_bcast<DPP_B1>(act);
        const float gv = dpp_bcast<DPP_B2>(act);   // already -2k-scaled
        const float ov = dpp_bcast<DPP_B3>(act);
        c = fmaf(fv, c, act * gv);                 // scaled domain
        const float rt = __builtin_amdgcn_rcpf(1.0f + __builtin_amdgcn_exp2f(c));
        const float h  = fmaf(ov + ov, rt, -ov);   // o * tanh(c_true)
        if (s == 0 && h16 < 3) *(wr_p + ofs) = (_Float16)h;
        __syncthreads();
    };

    for (int w = 0; w < TT / NS; ++w) {
        const int t0 = w * NS;
        if (w == 0) {
            if (tid < 48) ((uint32_t*)hist)[tid] = 0u;  // row 0 = h(-1) = 0
        } else {
            flush(t0 - NS);                              // old xs + rows 1..512
            if (tid < 48)                                // row 512 -> row 0
                ((uint32_t*)hist)[tid] = ((const uint32_t*)(hist + NS * ROWP))[tid];
        }
        __syncthreads();
        for (int i = tid; i < NS; i += TH) xs[i] = x[(t0 + i) * BB + b];
        __syncthreads();

        rd_p = hist + 8 * h16;
        rd_v = hist + 64 + 8 * s;
        wr_p = hist + ROWP + j;
        for (int tt = 0; tt < NS; tt += 4) {
            const float4 xq = *(const float4*)(xs + tt);  // broadcast
            const float gx0 = fmaf(xq.x, wih2, bias2);    // off-chain
            const float gx1 = fmaf(xq.y, wih2, bias2);
            const float gx2 = fmaf(xq.z, wih2, bias2);
            const float gx3 = fmaf(xq.w, wih2, bias2);
            step(gx0, 0 * ROWP);
            step(gx1, 1 * ROWP);
            step(gx2, 2 * ROWP);
            step(gx3, 3 * ROWP);
            rd_p += 4 * ROWP;
            rd_v += 4 * ROWP;
            wr_p += 4 * ROWP;
        }
    }
    flush(TT - NS);   // last window (loop ended with a barrier)
}

extern "C" void kernel_launch(void* const* d_in, const int* in_sizes, int n_in,
                              void* d_out, int out_size, void* d_ws, size_t ws_size,
                              hipStream_t stream) {
    const float* x    = (const float*)d_in[0];
    const float* w_ih = (const float*)d_in[1];
    const float* w_hh = (const float*)d_in[2];
    const float* b_ih = (const float*)d_in[3];
    const float* b_hh = (const float*)d_in[4];
    const float* fc_w = (const float*)d_in[5];
    const float* fc_b = (const float*)d_in[6];
    float* out = (float*)d_out;

    lstm_kernel<<<dim3(BB), dim3(TH), 0, stream>>>(x, w_ih, w_hh, b_ih, b_hh,
                                                   fc_w, fc_b, out);
}

// Round 14
// 4581.260 us; speedup vs baseline: 1.3118x; 1.3118x over previous
//
#include <hip/hip_runtime.h>

// LSTM T=16384, B=32, H=96. 32 blocks x 512 thr (8 waves, 2/SIMD).
// R20/R24 = 4580us -- VERIFIED OPTIMUM. This restores it verbatim.
// Session evidence (9 probes bracket this structure):
//   R18 6-wave 5142 (burst imbalance {2,2,1,1}); R21 12-wave 4968 (per-wave
//   redundant tail, +50% VALU issue); R22 VALU k-split 6102; R25 1-read+DPP
//   rebuild 4926; R26 k-split+XOR-butterfly 6010 -- together these refute
//   BOTH the LDS-queue model and the VALU-overlap model: in barrier-lockstep,
//   added work on ANY pipe extends step time near-linearly; nothing hides
//   under the MFMA burst. R23 persistent-acc 21650 (element-writes into live
//   MFMA C-regs defeat per-step renaming). R16/R19 dual domains 8286/6623
//   (co-resident recurrences can't shorten each other's serial chain).
// Floor arithmetic: matvec forces one rank-1 MFMA operand -> 512 useful
// MACs per 16x16x32 -> 72 MFMA/CU/step (f16 floor; fp8-MX K=128 would halve
// the pipe but 3-mantissa-bit h is an absmax risk). Step = exchange ~300cy
// (write->barrier->read, forced by h(t) all-to-all) + MFMA pipe ~350cy
// (18/SIMD x 19.4cy) with no legal overlap. R20 is within ~5% of this.
// Structure (HW-verified): A = h(t-1) replicated rows (3x ds_read_b128,
// k-slice 8*h16), B = weights cols (tile t col c -> cell 12wv+4t+(c>>2),
// gate c&3), gx seeded in C reg0 ({gx,0,0,0} fresh per step), te=min(h16,2)
// mirror for h16=3, quad DPP tail, e_k prefold, scaled-domain c' = -2k*c,
// 513-row slot-shifted history, one barrier/step, bulk fc flush per window.

constexpr int HH   = 96;
constexpr int BB   = 32;
constexpr int TT   = 16384;
constexpr int TH   = 512;   // 8 waves, 2 per SIMD
constexpr int NS   = 512;   // h history window
constexpr int ROWP = 104;   // halves per hist row: 208 B, 16B-aligned

typedef _Float16 f16x8 __attribute__((ext_vector_type(8)));
typedef _Float16 f16x2 __attribute__((ext_vector_type(2)));
typedef float    f32x4 __attribute__((ext_vector_type(4)));

template <int CTRL>
__device__ __forceinline__ float dpp_bcast(float v) {
    int r = __builtin_amdgcn_mov_dpp(__builtin_bit_cast(int, v), CTRL, 0xF, 0xF, true);
    return __builtin_bit_cast(float, r);
}
constexpr int DPP_B1 = 0x55;
constexpr int DPP_B2 = 0xAA;
constexpr int DPP_B3 = 0xFF;

#define LOG2E 1.44269504f

__attribute__((amdgpu_flat_work_group_size(TH, TH)))
__global__ void lstm_kernel(const float* __restrict__ x,
                            const float* __restrict__ w_ih,
                            const float* __restrict__ w_hh,
                            const float* __restrict__ b_ih,
                            const float* __restrict__ b_hh,
                            const float* __restrict__ fc_w,
                            const float* __restrict__ fc_b,
                            float* __restrict__ out) {
    __shared__ __align__(16) _Float16 hist[(NS + 1) * ROWP];  // ~104 KB
    __shared__ __align__(16) float xs[NS];                    // 2 KB x window
    __shared__ float fcw_s[HH];

    const int tid = threadIdx.x;
    const int b   = blockIdx.x;
    const int wv  = tid >> 6;   // wave 0..7, owns cells [12wv, 12wv+12)
    const int l   = tid & 63;
    const int h16 = l >> 4;     // k-group 0..3; tail tile = min(h16,2)
    const int rIn = l & 15;     // col within tile
    const int s   = rIn & 3;    // gate 0..3 (quad lane)
    const int q   = rIn >> 2;   // cell-sub within tile
    const int te  = (h16 == 3) ? 2 : h16;    // tail tile (h16=3 mirrors 2)
    const int j   = 12 * wv + 4 * te + q;    // this lane's cell 0..95

    // B fragments (weights), e_k-prescaled. Tile t col rIn holds W row
    // (gate s, cell 12wv+4t+q); lane's k slice = kt*32 + 8*h16 + e.
    const float ek_s = (s == 2) ? (-2.0f * LOG2E) : (-LOG2E);
    f16x8 Bw[3][3];
#pragma unroll
    for (int t = 0; t < 3; ++t) {
        const float* wrow = w_hh + (s * HH + 12 * wv + 4 * t + q) * HH;
#pragma unroll
        for (int kt = 0; kt < 3; ++kt) {
            const float* wr = wrow + kt * 32 + 8 * h16;
            f16x8 v;
#pragma unroll
            for (int e = 0; e < 8; ++e) v[e] = (_Float16)(wr[e] * ek_s);
            Bw[t][kt] = v;
        }
    }
#pragma unroll
    for (int t = 0; t < 3; ++t)
#pragma unroll
        for (int kt = 0; kt < 3; ++kt) asm volatile("" : "+v"(Bw[t][kt]));

    const float wih2  = w_ih[s * HH + j] * ek_s;
    const float bias2 = (b_ih[s * HH + j] + b_hh[s * HH + j]) * ek_s;
    const float a_mul = (s == 2) ? (-4.0f * LOG2E) : 1.0f;
    const float a_add = (s == 2) ? (2.0f * LOG2E) : 0.0f;
    const bool  te1 = (h16 == 1), te2 = (h16 >= 2);

    const float fcb = fc_b[0];
    float c = 0.0f;   // scaled domain: c' = -2*log2e * c_true

    for (int i = tid; i < HH; i += TH) fcw_s[i] = fc_w[i];

    // Bulk fc projection for window [t0, t0+NS): h(t0+i) is in hist row i+1.
    auto flush = [&](int t0) {
        for (int i = tid; i < NS; i += TH) {
            const uint2* hr = (const uint2*)(hist + (i + 1) * ROWP);
            float a = 0.0f;
#pragma unroll
            for (int m = 0; m < 24; ++m) {
                uint2 u = hr[m];
                f16x2 p0 = __builtin_bit_cast(f16x2, u.x);
                f16x2 p1 = __builtin_bit_cast(f16x2, u.y);
                a = fmaf((float)p0.x, fcw_s[4 * m + 0], a);
                a = fmaf((float)p0.y, fcw_s[4 * m + 1], a);
                a = fmaf((float)p1.x, fcw_s[4 * m + 2], a);
                a = fmaf((float)p1.y, fcw_s[4 * m + 3], a);
            }
            out[(t0 + i) * BB + b] = a + fcb + xs[i];
        }
    };

    const _Float16* rd_p;  // h(t-1) k-slice base (8*h16); +4 rows per block
    _Float16*       wr_p;  // h(t) cell slot base

    auto step = [&](float gx, const int ofs) {   // ofs: constant element offset
        const uint4* p = (const uint4*)(rd_p + ofs);
        uint4 u0 = p[0], u1 = p[4], u2 = p[8];   // kt stride: 32 halves = 64B
        const f16x8 a0 = __builtin_bit_cast(f16x8, u0);
        const f16x8 a1 = __builtin_bit_cast(f16x8, u1);
        const f16x8 a2 = __builtin_bit_cast(f16x8, u2);

        // C-init carries gx: lane (h16,rIn) seeds elem (row 4h16, col rIn)
        // of every tile and reads back exactly its own seed from tile te.
        // Fresh per-step init (movs hide under ds_read latency; R23 showed
        // element-writes into persistent acc regs serialize the loop).
        const f32x4 cz = {gx, 0.f, 0.f, 0.f};
        f32x4 acc[3] = {cz, cz, cz};
        // kt-outer: 3 tile-chains interleave; C-forwarding runs at full rate.
#pragma unroll
        for (int t = 0; t < 3; ++t)
            acc[t] = __builtin_amdgcn_mfma_f32_16x16x32_f16(a0, Bw[t][0], acc[t], 0, 0, 0);
#pragma unroll
        for (int t = 0; t < 3; ++t)
            acc[t] = __builtin_amdgcn_mfma_f32_16x16x32_f16(a1, Bw[t][1], acc[t], 0, 0, 0);
#pragma unroll
        for (int t = 0; t < 3; ++t)
            acc[t] = __builtin_amdgcn_mfma_f32_16x16x32_f16(a2, Bw[t][2], acc[t], 0, 0, 0);

        // Rows are replicas -> reg 0 always; 2-cndmask tile select by te.
        float pre = te1 ? acc[1][0] : acc[0][0];
        pre       = te2 ? acc[2][0] : pre;

        const float act =
            fmaf(__builtin_amdgcn_rcpf(1.0f + __builtin_amdgcn_exp2f(pre)),
                 a_mul, a_add);
        const float fv = dpp_bcast<DPP_B1>(act);
        const float gv = dpp_bcast<DPP_B2>(act);   // already -2k-scaled
        const float ov = dpp_bcast<DPP_B3>(act);
        c = fmaf(fv, c, act * gv);                 // scaled domain
        const float rt = __builtin_amdgcn_rcpf(1.0f + __builtin_amdgcn_exp2f(c));
        const float h  = fmaf(ov + ov, rt, -ov);   // o * tanh(c_true)
        if (s == 0 && h16 < 3) *(wr_p + ofs) = (_Float16)h;
        __syncthreads();
    };

    for (int w = 0; w < TT / NS; ++w) {
        const int t0 = w * NS;
        if (w == 0) {
            if (tid < 48) ((uint32_t*)hist)[tid] = 0u;  // row 0 = h(-1) = 0
        } else {
            flush(t0 - NS);                              // old xs + rows 1..512
            if (tid < 48)                                // row 512 -> row 0
                ((uint32_t*)hist)[tid] = ((const uint32_t*)(hist + NS * ROWP))[tid];
        }
        __syncthreads();
        for (int i = tid; i < NS; i += TH) xs[i] = x[(t0 + i) * BB + b];
        __syncthreads();

        rd_p = hist + 8 * h16;
        wr_p = hist + ROWP + j;
        for (int tt = 0; tt < NS; tt += 4) {
            const float4 xq = *(const float4*)(xs + tt);  // broadcast
            const float gx0 = fmaf(xq.x, wih2, bias2);    // off-chain
            const float gx1 = fmaf(xq.y, wih2, bias2);
            const float gx2 = fmaf(xq.z, wih2, bias2);
            const float gx3 = fmaf(xq.w, wih2, bias2);
            step(gx0, 0 * ROWP);
            step(gx1, 1 * ROWP);
            step(gx2, 2 * ROWP);
            step(gx3, 3 * ROWP);
            rd_p += 4 * ROWP;
            wr_p += 4 * ROWP;
        }
    }
    flush(TT - NS);   // last window (loop ended with a barrier)
}

extern "C" void kernel_launch(void* const* d_in, const int* in_sizes, int n_in,
                              void* d_out, int out_size, void* d_ws, size_t ws_size,
                              hipStream_t stream) {
    const float* x    = (const float*)d_in[0];
    const float* w_ih = (const float*)d_in[1];
    const float* w_hh = (const float*)d_in[2];
    const float* b_ih = (const float*)d_in[3];
    const float* b_hh = (const float*)d_in[4];
    const float* fc_w = (const float*)d_in[5];
    const float* fc_b = (const float*)d_in[6];
    float* out = (float*)d_out;

    lstm_kernel<<<dim3(BB), dim3(TH), 0, stream>>>(x, w_ih, w_hh, b_ih, b_hh,
                                                   fc_w, fc_b, out);
}